// Round 1
// baseline (2074.479 us; speedup 1.0000x reference)
//
#include <hip/hip_runtime.h>
#include <hip/hip_bf16.h>

#define NE 8
#define DD 1024
#define HH 4096
#define NTOK 8192
#define CH 4096   // h-buffer chunk rows

typedef float f32x4 __attribute__((ext_vector_type(4)));
typedef ushort u16x4 __attribute__((ext_vector_type(4)));
typedef ushort u16x8 __attribute__((ext_vector_type(8)));
typedef short s16x8 __attribute__((ext_vector_type(8)));

__device__ inline ushort f2bf(float f) {
    unsigned u = __builtin_bit_cast(unsigned, f);
    u += 0x7fffu + ((u >> 16) & 1u);   // RNE
    return (ushort)(u >> 16);
}
__device__ inline u16x4 lo4(u16x8 v) { return __builtin_shufflevector(v, v, 0, 1, 2, 3); }
__device__ inline u16x4 hi4(u16x8 v) { return __builtin_shufflevector(v, v, 4, 5, 6, 7); }

// ---------------- gating: fp32 logits, softmax, top-2, build expert lists ---------
__global__ void gate_kernel(const float* __restrict__ x, const float* __restrict__ Wg,
                            const float* __restrict__ bg, int* __restrict__ cnt,
                            int* __restrict__ list, float* __restrict__ wl) {
    const int lane = threadIdx.x & 63;
    const int t = blockIdx.x * 4 + (threadIdx.x >> 6);
    float part[NE] = {};
    const float* xp = x + (size_t)t * DD + lane;
    for (int i = 0; i < DD / 64; i++) {
        float xv = xp[i * 64];
        const f32x4* wrow = (const f32x4*)(Wg + (size_t)(lane + i * 64) * NE);
        f32x4 w0 = wrow[0], w1 = wrow[1];
        part[0] += xv * w0[0]; part[1] += xv * w0[1]; part[2] += xv * w0[2]; part[3] += xv * w0[3];
        part[4] += xv * w1[0]; part[5] += xv * w1[1]; part[6] += xv * w1[2]; part[7] += xv * w1[3];
    }
    float l[NE];
    for (int e = 0; e < NE; e++) {
        float v = part[e];
        for (int off = 32; off > 0; off >>= 1) v += __shfl_xor(v, off);
        l[e] = v + bg[e];
    }
    if (lane == 0) {
        int i0 = 0; float m0 = l[0];
        for (int e = 1; e < NE; e++) if (l[e] > m0) { m0 = l[e]; i0 = e; }
        int i1 = -1; float m1 = -3.4e38f;
        for (int e = 0; e < NE; e++) if (e != i0 && l[e] > m1) { m1 = l[e]; i1 = e; }
        float s = 0.f;
        for (int e = 0; e < NE; e++) s += expf(l[e] - m0);
        float w0v = 1.0f / s;
        float w1v = expf(m1 - m0) / s;
        int s0 = atomicAdd(cnt + i0, 1);
        list[i0 * NTOK + s0] = t; wl[i0 * NTOK + s0] = w0v;
        int s1 = atomicAdd(cnt + i1, 1);
        list[i1 * NTOK + s1] = t; wl[i1 * NTOK + s1] = w1v;
    }
}

// ---------------- transpose + fp32->bf16 convert: out[C][R] = in[R][C] -----------
__global__ void transpose_cvt(const float* __restrict__ in, ushort* __restrict__ out,
                              int R, int C) {
    __shared__ float t[32][33];
    const int c0 = blockIdx.x * 32, r0 = blockIdx.y * 32;
    const int x = threadIdx.x, y = threadIdx.y;
    for (int j = 0; j < 4; j++)
        t[y + j * 8][x] = in[(size_t)(r0 + y + j * 8) * C + c0 + x];
    __syncthreads();
    for (int j = 0; j < 4; j++)
        out[(size_t)(c0 + y + j * 8) * R + r0 + x] = f2bf(t[x][y + j * 8]);
}

// ---------------- tiled MFMA GEMM over one expert's token list -------------------
// IS_G1: A = gathered x rows (fp32->bf16), out = relu(acc+b1) -> h (bf16)
// else : A = h rows (bf16),               out += wgt*(acc+b2) via atomicAdd
template <int IS_G1>
__global__ __launch_bounds__(256, 2) void moe_gemm(
    const float* __restrict__ Ax, const ushort* __restrict__ Ah,
    const ushort* __restrict__ BT, const float* __restrict__ bias,
    const int* __restrict__ cntp, const int* __restrict__ list,
    const float* __restrict__ wl, ushort* __restrict__ hout,
    float* __restrict__ out, const int Kdim, const int ldout, const int chunk0) {
    const int cnt = *cntp;
    const int r0 = chunk0 + blockIdx.x * 128;
    if (r0 >= cnt) return;
    const int n0 = blockIdx.y * 128;

    __shared__ __align__(16) ushort As[128][40];
    __shared__ __align__(16) ushort Bs[128][40];

    const int tid = threadIdx.x;
    const int lane = tid & 63;
    const int wv = tid >> 6;
    const int wr = (wv >> 1) * 64;
    const int wc = (wv & 1) * 64;

    // staging coords: thread covers row sr, 16 consecutive k at skh
    const int sr = tid >> 1;
    const int skh = (tid & 1) * 16;
    const int pb = (tid & 1) * 4;   // permuted base within each 8-slot group

    const float* ax = nullptr;
    const ushort* ah = nullptr;
    {
        int slot = r0 + sr;
        if (slot >= cnt) slot = cnt - 1;
        if (IS_G1) ax = Ax + (size_t)list[slot] * (size_t)Kdim + skh;
        else       ah = Ah + (size_t)(slot - chunk0) * (size_t)Kdim + skh;
    }
    const ushort* bsrc = BT + (size_t)(n0 + sr) * (size_t)Kdim + skh;

    f32x4 acc[4][4] = {};
    const int fr = lane & 15;
    const int g = lane >> 4;

    for (int k0 = 0; k0 < Kdim; k0 += 32) {
        // ---- stage A ----
        if (IS_G1) {
            f32x4 v0 = *(const f32x4*)(ax + k0);
            f32x4 v1 = *(const f32x4*)(ax + k0 + 4);
            f32x4 v2 = *(const f32x4*)(ax + k0 + 8);
            f32x4 v3 = *(const f32x4*)(ax + k0 + 12);
            u16x4 q0 = {f2bf(v0[0]), f2bf(v0[1]), f2bf(v0[2]), f2bf(v0[3])};
            u16x4 q1 = {f2bf(v1[0]), f2bf(v1[1]), f2bf(v1[2]), f2bf(v1[3])};
            u16x4 q2 = {f2bf(v2[0]), f2bf(v2[1]), f2bf(v2[2]), f2bf(v2[3])};
            u16x4 q3 = {f2bf(v3[0]), f2bf(v3[1]), f2bf(v3[2]), f2bf(v3[3])};
            *(u16x4*)&As[sr][0 + pb] = q0;
            *(u16x4*)&As[sr][8 + pb] = q1;
            *(u16x4*)&As[sr][16 + pb] = q2;
            *(u16x4*)&As[sr][24 + pb] = q3;
        } else {
            u16x8 ra0 = *(const u16x8*)(ah + k0);
            u16x8 ra1 = *(const u16x8*)(ah + k0 + 8);
            *(u16x4*)&As[sr][0 + pb] = lo4(ra0);
            *(u16x4*)&As[sr][8 + pb] = hi4(ra0);
            *(u16x4*)&As[sr][16 + pb] = lo4(ra1);
            *(u16x4*)&As[sr][24 + pb] = hi4(ra1);
        }
        // ---- stage B ----
        {
            u16x8 rb0 = *(const u16x8*)(bsrc + k0);
            u16x8 rb1 = *(const u16x8*)(bsrc + k0 + 8);
            *(u16x4*)&Bs[sr][0 + pb] = lo4(rb0);
            *(u16x4*)&Bs[sr][8 + pb] = hi4(rb0);
            *(u16x4*)&Bs[sr][16 + pb] = lo4(rb1);
            *(u16x4*)&Bs[sr][24 + pb] = hi4(rb1);
        }
        __syncthreads();
        // ---- compute ----
        s16x8 a[4], b[4];
#pragma unroll
        for (int m = 0; m < 4; m++) a[m] = *(const s16x8*)&As[wr + m * 16 + fr][g * 8];
#pragma unroll
        for (int n = 0; n < 4; n++) b[n] = *(const s16x8*)&Bs[wc + n * 16 + fr][g * 8];
#pragma unroll
        for (int m = 0; m < 4; m++)
#pragma unroll
            for (int n = 0; n < 4; n++)
                acc[m][n] = __builtin_amdgcn_mfma_f32_16x16x32_bf16(a[m], b[n], acc[m][n], 0, 0, 0);
        __syncthreads();
    }

    // ---- epilogue ----
    if (IS_G1) {
#pragma unroll
        for (int m = 0; m < 4; m++) {
            const int rb = wr + m * 16 + (g << 2);
#pragma unroll
            for (int n = 0; n < 4; n++) {
                const int col = n0 + wc + n * 16 + fr;
                const float bv = bias[col];
#pragma unroll
                for (int r = 0; r < 4; r++) {
                    const int slot = r0 + rb + r;
                    if (slot < cnt) {
                        float v = acc[m][n][r] + bv;
                        v = v > 0.f ? v : 0.f;
                        hout[(size_t)(slot - chunk0) * ldout + col] = f2bf(v);
                    }
                }
            }
        }
    } else {
#pragma unroll
        for (int m = 0; m < 4; m++) {
            const int rb = r0 + wr + m * 16 + (g << 2);
#pragma unroll
            for (int r = 0; r < 4; r++) {
                const int slot = rb + r;
                if (slot < cnt) {
                    const int tok = list[slot];
                    const float wgt = wl[slot];
#pragma unroll
                    for (int n = 0; n < 4; n++) {
                        const int col = n0 + wc + n * 16 + fr;
                        atomicAdd(out + (size_t)tok * ldout + col,
                                  wgt * (acc[m][n][r] + bias[col]));
                    }
                }
            }
        }
    }
}

extern "C" void kernel_launch(void* const* d_in, const int* in_sizes, int n_in,
                              void* d_out, int out_size, void* d_ws, size_t ws_size,
                              hipStream_t stream) {
    const float* x  = (const float*)d_in[0];
    const float* Wg = (const float*)d_in[1];
    const float* bg = (const float*)d_in[2];
    const float* W1 = (const float*)d_in[3];
    const float* b1 = (const float*)d_in[4];
    const float* W2 = (const float*)d_in[5];
    const float* b2 = (const float*)d_in[6];
    float* out = (float*)d_out;

    char* w = (char*)d_ws;
    int* cnt = (int*)w;                              // 64 B
    int* list = (int*)(w + 256);                     // NE*NTOK*4 = 256 KB
    float* wl = (float*)(w + 256 + (size_t)NE * NTOK * 4);
    size_t off = 256 + 2 * (size_t)NE * NTOK * 4;
    off = (off + 255) & ~(size_t)255;
    ushort* W1T = (ushort*)(w + off); off += (size_t)DD * HH * 2;   // 8 MB
    ushort* W2T = (ushort*)(w + off); off += (size_t)HH * DD * 2;   // 8 MB
    ushort* hbuf = (ushort*)(w + off); off += (size_t)CH * HH * 2;  // 32 MB

    if (ws_size < off) {  // ws too small: deterministic zero output as a signal
        hipMemsetAsync(d_out, 0, (size_t)NTOK * DD * 4, stream);
        return;
    }

    hipMemsetAsync(cnt, 0, 64, stream);
    hipMemsetAsync(out, 0, (size_t)NTOK * DD * 4, stream);
    gate_kernel<<<NTOK / 4, 256, 0, stream>>>(x, Wg, bg, cnt, list, wl);

    for (int e = 0; e < NE; e++) {
        transpose_cvt<<<dim3(HH / 32, DD / 32), dim3(32, 8), 0, stream>>>(
            W1 + (size_t)e * DD * HH, W1T, DD, HH);
        transpose_cvt<<<dim3(DD / 32, HH / 32), dim3(32, 8), 0, stream>>>(
            W2 + (size_t)e * HH * DD, W2T, HH, DD);
        for (int c = 0; c < NTOK / CH; c++) {
            moe_gemm<1><<<dim3(CH / 128, HH / 128), 256, 0, stream>>>(
                x, nullptr, W1T, b1 + (size_t)e * HH, cnt + e, list + e * NTOK,
                wl + e * NTOK, hbuf, nullptr, DD, HH, c * CH);
            moe_gemm<0><<<dim3(CH / 128, DD / 128), 256, 0, stream>>>(
                nullptr, hbuf, W2T, b2 + (size_t)e * DD, cnt + e, list + e * NTOK,
                wl + e * NTOK, nullptr, out, HH, DD, c * CH);
        }
    }
}

// Round 7
// 1484.925 us; speedup vs baseline: 1.3970x; 1.3970x over previous
//
#include <hip/hip_runtime.h>
#include <hip/hip_bf16.h>

#define NE 8
#define DD 1024
#define HH 4096
#define NTOK 8192
#define CH 2048   // h-buffer chunk rows (16 MB bf16) — keeps ws ~= R1's proven 48.5 MB

typedef float f32x4 __attribute__((ext_vector_type(4)));
typedef ushort u16x8 __attribute__((ext_vector_type(8)));
typedef short s16x8 __attribute__((ext_vector_type(8)));

__device__ inline ushort f2bf(float f) {
    unsigned u = __builtin_bit_cast(unsigned, f);
    u += 0x7fffu + ((u >> 16) & 1u);   // RNE
    return (ushort)(u >> 16);
}

__device__ __forceinline__ void gl_lds16(const ushort* g, ushort* l) {
    __builtin_amdgcn_global_load_lds(
        (const __attribute__((address_space(1))) void*)g,
        (__attribute__((address_space(3))) void*)l, 16, 0, 0);
}

// ---------------- x fp32 -> bf16 ----------------
__global__ void cvt_x(const float* __restrict__ x, ushort* __restrict__ xbf) {
    const size_t i = ((size_t)blockIdx.x * 256 + threadIdx.x) * 8;
    f32x4 a = *(const f32x4*)(x + i);
    f32x4 b = *(const f32x4*)(x + i + 4);
    u16x8 o = {f2bf(a[0]), f2bf(a[1]), f2bf(a[2]), f2bf(a[3]),
               f2bf(b[0]), f2bf(b[1]), f2bf(b[2]), f2bf(b[3])};
    *(u16x8*)(xbf + i) = o;
}

// ---------------- gating: fp32 logits, softmax, top-2 (NO atomics) ---------------
__global__ void gate_compute(const float* __restrict__ x, const float* __restrict__ Wg,
                             const float* __restrict__ bg, int2* __restrict__ topi,
                             float2* __restrict__ topw) {
    const int lane = threadIdx.x & 63;
    const int t = blockIdx.x * 4 + (threadIdx.x >> 6);
    float part[NE] = {};
    const float* xp = x + (size_t)t * DD + lane;
    for (int i = 0; i < DD / 64; i++) {
        float xv = xp[i * 64];
        const f32x4* wrow = (const f32x4*)(Wg + (size_t)(lane + i * 64) * NE);
        f32x4 w0 = wrow[0], w1 = wrow[1];
        part[0] += xv * w0[0]; part[1] += xv * w0[1]; part[2] += xv * w0[2]; part[3] += xv * w0[3];
        part[4] += xv * w1[0]; part[5] += xv * w1[1]; part[6] += xv * w1[2]; part[7] += xv * w1[3];
    }
    float l[NE];
    for (int e = 0; e < NE; e++) {
        float v = part[e];
        for (int off = 32; off > 0; off >>= 1) v += __shfl_xor(v, off);
        l[e] = v + bg[e];
    }
    if (lane == 0) {
        int i0 = 0; float m0 = l[0];
        for (int e = 1; e < NE; e++) if (l[e] > m0) { m0 = l[e]; i0 = e; }
        int i1 = -1; float m1 = -3.4e38f;
        for (int e = 0; e < NE; e++) if (e != i0 && l[e] > m1) { m1 = l[e]; i1 = e; }
        float s = 0.f;
        for (int e = 0; e < NE; e++) s += expf(l[e] - m0);
        topi[t] = make_int2(i0, i1);
        topw[t] = make_float2(1.0f / s, expf(m1 - m0) / s);
    }
}

// ---------------- build per-expert token lists via block prefix-scan -------------
__global__ void build_lists(const int2* __restrict__ topi, const float2* __restrict__ topw,
                            int* __restrict__ cnt, int* __restrict__ list,
                            float* __restrict__ wl) {
    const int e = blockIdx.x;
    const int tid = threadIdx.x;
    const int lane = tid & 63, wv = tid >> 6;
    __shared__ int wsum[4];
    __shared__ int sbase;
    if (tid == 0) sbase = 0;
    __syncthreads();
    for (int t0 = 0; t0 < NTOK; t0 += 256) {
        const int tok = t0 + tid;
        const int2 ti = topi[tok];
        const float2 tw = topw[tok];
        const bool hit0 = (ti.x == e), hit1 = (ti.y == e);
        const bool hit = hit0 || hit1;
        const unsigned long long ball = __ballot(hit);
        const int pre = __popcll(ball & ((1ull << lane) - 1ull));
        if (lane == 0) wsum[wv] = __popcll(ball);
        __syncthreads();
        int wbase = 0;
        for (int i = 0; i < wv; i++) wbase += wsum[i];
        const int total = wsum[0] + wsum[1] + wsum[2] + wsum[3];
        const int mybase = sbase;
        if (hit) {
            const int pos = mybase + wbase + pre;
            list[e * NTOK + pos] = tok;
            wl[e * NTOK + pos] = hit0 ? tw.x : tw.y;
        }
        __syncthreads();
        if (tid == 0) sbase = mybase + total;
        __syncthreads();
    }
    if (tid == 0) cnt[e] = sbase;
}

// ---------------- transpose + fp32->bf16 convert: out[C][R] = in[R][C] -----------
__global__ void transpose_cvt(const float* __restrict__ in, ushort* __restrict__ out,
                              int R, int C) {
    __shared__ float t[32][33];
    const int c0 = blockIdx.x * 32, r0 = blockIdx.y * 32;
    const int x = threadIdx.x, y = threadIdx.y;
    for (int j = 0; j < 4; j++)
        t[y + j * 8][x] = in[(size_t)(r0 + y + j * 8) * C + c0 + x];
    __syncthreads();
    for (int j = 0; j < 4; j++)
        out[(size_t)(c0 + y + j * 8) * R + r0 + x] = f2bf(t[x][y + j * 8]);
}

// ---------------- m97-style tiled MFMA GEMM over one expert's token list ---------
// IS_G1: A = gathered xbf rows, out = relu(acc+b1) -> hbuf (bf16)
// else : A = hbuf rows, split-K over blockIdx.z, out += wgt*(acc[+b2]) atomically
template <int IS_G1>
__global__ __launch_bounds__(256, 2) void moe_gemm(
    const ushort* __restrict__ Abase, const ushort* __restrict__ BT,
    const float* __restrict__ bias, const int* __restrict__ cntp,
    const int* __restrict__ list, const float* __restrict__ wl,
    ushort* __restrict__ hout, float* __restrict__ out,
    const int lda, const int ldb, const int ldout, const int chunk0) {
    const int cnt = *cntp;
    const int r0 = chunk0 + blockIdx.x * 128;
    if (r0 >= cnt) return;
    const int n0 = blockIdx.y * 128;
    const int kb = IS_G1 ? 0 : blockIdx.z * (HH / 4);   // split-K base (GEMM2)

    __shared__ __align__(16) ushort As[128 * 32];
    __shared__ __align__(16) ushort Bs[128 * 32];

    const int tid = threadIdx.x;
    const int lane = tid & 63, wv = tid >> 6;
    const int wr = (wv >> 1) * 64, wc = (wv & 1) * 64;

    // staging: lane covers row wv*16 + lane/4 (+64 on round 1), 16 B at k=(lane&3)*8
    const int srow = wv * 16 + (lane >> 2);
    const int skq = (lane & 3) * 8;

    const ushort *aptr0, *aptr1;
    {
        int s0 = r0 + srow;       if (s0 >= cnt) s0 = cnt - 1;
        int s1 = r0 + 64 + srow;  if (s1 >= cnt) s1 = cnt - 1;
        if (IS_G1) {
            aptr0 = Abase + (size_t)list[s0] * lda + skq;
            aptr1 = Abase + (size_t)list[s1] * lda + skq;
        } else {
            aptr0 = Abase + (size_t)(s0 - chunk0) * lda + kb + skq;
            aptr1 = Abase + (size_t)(s1 - chunk0) * lda + kb + skq;
        }
    }
    const ushort* bptr0 = BT + (size_t)(n0 + srow) * ldb + kb + skq;
    const ushort* bptr1 = BT + (size_t)(n0 + 64 + srow) * ldb + kb + skq;

    // wave-uniform LDS bases (lane l lands at base + l*16 B = row wv*16+l/4, quarter l&3)
    ushort* As0 = As + (size_t)(wv * 16) * 32;
    ushort* As1 = As + (size_t)(64 + wv * 16) * 32;
    ushort* Bs0 = Bs + (size_t)(wv * 16) * 32;
    ushort* Bs1 = Bs + (size_t)(64 + wv * 16) * 32;

    f32x4 acc[4][4] = {};
    const int fr = lane & 15, g = lane >> 4;

    const int KT = IS_G1 ? (DD / 32) : (HH / 4 / 32);
    for (int kt = 0; kt < KT; kt++) {
        const int ke = kt * 32;
        gl_lds16(aptr0 + ke, As0);
        gl_lds16(aptr1 + ke, As1);
        gl_lds16(bptr0 + ke, Bs0);
        gl_lds16(bptr1 + ke, Bs1);
        __syncthreads();
        s16x8 a[4], b[4];
#pragma unroll
        for (int m = 0; m < 4; m++) a[m] = *(const s16x8*)(As + (wr + m * 16 + fr) * 32 + g * 8);
#pragma unroll
        for (int n = 0; n < 4; n++) b[n] = *(const s16x8*)(Bs + (wc + n * 16 + fr) * 32 + g * 8);
#pragma unroll
        for (int m = 0; m < 4; m++)
#pragma unroll
            for (int n = 0; n < 4; n++)
                acc[m][n] = __builtin_amdgcn_mfma_f32_16x16x32_bf16(a[m], b[n], acc[m][n], 0, 0, 0);
        __syncthreads();
    }

    // ---- epilogue ----
    if (IS_G1) {
#pragma unroll
        for (int m = 0; m < 4; m++) {
            const int rb = wr + m * 16 + (g << 2);
#pragma unroll
            for (int n = 0; n < 4; n++) {
                const int col = n0 + wc + n * 16 + fr;
                const float bv = bias[col];
#pragma unroll
                for (int r = 0; r < 4; r++) {
                    const int slot = r0 + rb + r;
                    if (slot < cnt) {
                        float v = acc[m][n][r] + bv;
                        v = v > 0.f ? v : 0.f;
                        hout[(size_t)(slot - chunk0) * ldout + col] = f2bf(v);
                    }
                }
            }
        }
    } else {
        const bool kz0 = (blockIdx.z == 0);
#pragma unroll
        for (int m = 0; m < 4; m++) {
            const int rb = r0 + wr + m * 16 + (g << 2);
#pragma unroll
            for (int r = 0; r < 4; r++) {
                const int slot = rb + r;
                if (slot < cnt) {
                    const int tok = list[slot];
                    const float wgt = wl[slot];
#pragma unroll
                    for (int n = 0; n < 4; n++) {
                        const int col = n0 + wc + n * 16 + fr;
                        const float bv = kz0 ? bias[col] : 0.f;
                        atomicAdd(out + (size_t)tok * ldout + col,
                                  wgt * (acc[m][n][r] + bv));
                    }
                }
            }
        }
    }
}

extern "C" void kernel_launch(void* const* d_in, const int* in_sizes, int n_in,
                              void* d_out, int out_size, void* d_ws, size_t ws_size,
                              hipStream_t stream) {
    const float* x  = (const float*)d_in[0];
    const float* Wg = (const float*)d_in[1];
    const float* bg = (const float*)d_in[2];
    const float* W1 = (const float*)d_in[3];
    const float* b1 = (const float*)d_in[4];
    const float* W2 = (const float*)d_in[5];
    const float* b2 = (const float*)d_in[6];
    float* out = (float*)d_out;

    char* w = (char*)d_ws;
    int* cnt = (int*)w;
    size_t off = 256;
    int* list = (int*)(w + off);    off += (size_t)NE * NTOK * 4;
    float* wl = (float*)(w + off);  off += (size_t)NE * NTOK * 4;
    int2* topi = (int2*)(w + off);  off += (size_t)NTOK * 8;
    float2* topw = (float2*)(w + off); off += (size_t)NTOK * 8;
    off = (off + 255) & ~(size_t)255;
    ushort* W1T = (ushort*)(w + off); off += (size_t)DD * HH * 2;    // 8 MB
    ushort* W2T = (ushort*)(w + off); off += (size_t)HH * DD * 2;    // 8 MB
    ushort* xbf = (ushort*)(w + off); off += (size_t)NTOK * DD * 2;  // 16 MB
    ushort* hbuf = (ushort*)(w + off); off += (size_t)CH * HH * 2;   // 16 MB

    if (ws_size < off) {  // ws too small: deterministic zero output as a signal
        hipMemsetAsync(d_out, 0, (size_t)NTOK * DD * 4, stream);
        return;
    }

    hipMemsetAsync(out, 0, (size_t)NTOK * DD * 4, stream);
    cvt_x<<<NTOK * DD / 8 / 256, 256, 0, stream>>>(x, xbf);
    gate_compute<<<NTOK / 4, 256, 0, stream>>>(x, Wg, bg, topi, topw);
    build_lists<<<NE, 256, 0, stream>>>(topi, topw, cnt, list, wl);

    for (int e = 0; e < NE; e++) {
        transpose_cvt<<<dim3(HH / 32, DD / 32), dim3(32, 8), 0, stream>>>(
            W1 + (size_t)e * DD * HH, W1T, DD, HH);
        transpose_cvt<<<dim3(DD / 32, HH / 32), dim3(32, 8), 0, stream>>>(
            W2 + (size_t)e * HH * DD, W2T, HH, DD);
        for (int c = 0; c < NTOK / CH; c++) {
            moe_gemm<1><<<dim3(CH / 128, HH / 128), 256, 0, stream>>>(
                xbf, W1T, b1 + (size_t)e * HH, cnt + e, list + e * NTOK,
                wl + e * NTOK, hbuf, nullptr, DD, DD, HH, c * CH);
            moe_gemm<0><<<dim3(CH / 128, DD / 128, 4), 256, 0, stream>>>(
                hbuf, W2T, b2 + (size_t)e * DD, cnt + e, list + e * NTOK,
                wl + e * NTOK, nullptr, out, HH, HH, DD, c * CH);
        }
    }
}

// Round 8
// 996.840 us; speedup vs baseline: 2.0811x; 1.4896x over previous
//
#include <hip/hip_runtime.h>
#include <hip/hip_bf16.h>

#define NE 8
#define DD 1024
#define HH 4096
#define NTOK 8192
#define SPLITK 4
#define MAXT (NTOK * 2 / 128 + NE)   // 136 worst-case tiles across all experts

typedef float f32x4 __attribute__((ext_vector_type(4)));
typedef ushort u16x8 __attribute__((ext_vector_type(8)));
typedef short s16x8 __attribute__((ext_vector_type(8)));

__device__ inline ushort f2bf(float f) {
    unsigned u = __builtin_bit_cast(unsigned, f);
    u += 0x7fffu + ((u >> 16) & 1u);   // RNE
    return (ushort)(u >> 16);
}

__device__ __forceinline__ void gl_lds16(const ushort* g, ushort* l) {
    __builtin_amdgcn_global_load_lds(
        (const __attribute__((address_space(1))) void*)g,
        (__attribute__((address_space(3))) void*)l, 16, 0, 0);
}

// ---------------- x fp32 -> bf16 ----------------
__global__ void cvt_x(const float* __restrict__ x, ushort* __restrict__ xbf) {
    const size_t i = ((size_t)blockIdx.x * 256 + threadIdx.x) * 8;
    f32x4 a = *(const f32x4*)(x + i);
    f32x4 b = *(const f32x4*)(x + i + 4);
    u16x8 o = {f2bf(a[0]), f2bf(a[1]), f2bf(a[2]), f2bf(a[3]),
               f2bf(b[0]), f2bf(b[1]), f2bf(b[2]), f2bf(b[3])};
    *(u16x8*)(xbf + i) = o;
}

// ---------------- gating: fp32 logits, softmax, top-2 (NO atomics) ---------------
__global__ void gate_compute(const float* __restrict__ x, const float* __restrict__ Wg,
                             const float* __restrict__ bg, int2* __restrict__ topi,
                             float2* __restrict__ topw) {
    const int lane = threadIdx.x & 63;
    const int t = blockIdx.x * 4 + (threadIdx.x >> 6);
    float part[NE] = {};
    const float* xp = x + (size_t)t * DD + lane;
    for (int i = 0; i < DD / 64; i++) {
        float xv = xp[i * 64];
        const f32x4* wrow = (const f32x4*)(Wg + (size_t)(lane + i * 64) * NE);
        f32x4 w0 = wrow[0], w1 = wrow[1];
        part[0] += xv * w0[0]; part[1] += xv * w0[1]; part[2] += xv * w0[2]; part[3] += xv * w0[3];
        part[4] += xv * w1[0]; part[5] += xv * w1[1]; part[6] += xv * w1[2]; part[7] += xv * w1[3];
    }
    float l[NE];
    for (int e = 0; e < NE; e++) {
        float v = part[e];
        for (int off = 32; off > 0; off >>= 1) v += __shfl_xor(v, off);
        l[e] = v + bg[e];
    }
    if (lane == 0) {
        int i0 = 0; float m0 = l[0];
        for (int e = 1; e < NE; e++) if (l[e] > m0) { m0 = l[e]; i0 = e; }
        int i1 = -1; float m1 = -3.4e38f;
        for (int e = 0; e < NE; e++) if (e != i0 && l[e] > m1) { m1 = l[e]; i1 = e; }
        float s = 0.f;
        for (int e = 0; e < NE; e++) s += expf(l[e] - m0);
        topi[t] = make_int2(i0, i1);
        topw[t] = make_float2(1.0f / s, expf(m1 - m0) / s);
    }
}

// ---------------- build per-expert token lists via block prefix-scan -------------
__global__ void build_lists(const int2* __restrict__ topi, const float2* __restrict__ topw,
                            int* __restrict__ cnt, int* __restrict__ list,
                            float* __restrict__ wl) {
    const int e = blockIdx.x;
    const int tid = threadIdx.x;
    const int lane = tid & 63, wv = tid >> 6;
    __shared__ int wsum[4];
    __shared__ int sbase;
    if (tid == 0) sbase = 0;
    __syncthreads();
    for (int t0 = 0; t0 < NTOK; t0 += 256) {
        const int tok = t0 + tid;
        const int2 ti = topi[tok];
        const float2 tw = topw[tok];
        const bool hit0 = (ti.x == e), hit1 = (ti.y == e);
        const bool hit = hit0 || hit1;
        const unsigned long long ball = __ballot(hit);
        const int pre = __popcll(ball & ((1ull << lane) - 1ull));
        if (lane == 0) wsum[wv] = __popcll(ball);
        __syncthreads();
        int wbase = 0;
        for (int i = 0; i < wv; i++) wbase += wsum[i];
        const int total = wsum[0] + wsum[1] + wsum[2] + wsum[3];
        const int mybase = sbase;
        if (hit) {
            const int pos = mybase + wbase + pre;
            list[e * NTOK + pos] = tok;
            wl[e * NTOK + pos] = hit0 ? tw.x : tw.y;
        }
        __syncthreads();
        if (tid == 0) sbase = mybase + total;
        __syncthreads();
    }
    if (tid == 0) cnt[e] = sbase;
}

// ---------------- per-call tile/row prefix tables (1 thread — trivial) -----------
__global__ void tile_prefix(const int* __restrict__ cnt, int* __restrict__ tp,
                            int* __restrict__ cb) {
    if (threadIdx.x == 0) {
        int t = 0, c = 0;
        for (int e = 0; e < NE; e++) {
            tp[e] = t; cb[e] = c;
            t += (cnt[e] + 127) >> 7;
            c += cnt[e];
        }
        tp[NE] = t; cb[NE] = c;
    }
}

// ---------------- transpose + fp32->bf16, all experts via blockIdx.z -------------
// out[z][C][R] = in[z][R][C]
__global__ void transpose_cvt(const float* __restrict__ in, ushort* __restrict__ out,
                              int R, int C) {
    __shared__ float t[32][33];
    const float* ine = in + (size_t)blockIdx.z * R * C;
    ushort* oute = out + (size_t)blockIdx.z * R * C;
    const int c0 = blockIdx.x * 32, r0 = blockIdx.y * 32;
    const int x = threadIdx.x, y = threadIdx.y;
    for (int j = 0; j < 4; j++)
        t[y + j * 8][x] = ine[(size_t)(r0 + y + j * 8) * C + c0 + x];
    __syncthreads();
    for (int j = 0; j < 4; j++)
        oute[(size_t)(c0 + y + j * 8) * R + r0 + x] = f2bf(t[x][y + j * 8]);
}

// ---------------- grouped m97-style MFMA GEMM over ALL experts' token lists ------
// blockIdx.x = global tile id -> (expert, row block) via tp[] prefix table.
// IS_G1: A = gathered xbf rows, out = relu(acc+b1) -> hbuf row cb[e]+slot (bf16)
// else : A = hbuf rows,  split-K over blockIdx.z, out += wgt*(acc[+b2]) atomically
template <int IS_G1>
__global__ __launch_bounds__(256, 2) void moe_gemm(
    const ushort* __restrict__ Abase, const ushort* __restrict__ Ball,
    const float* __restrict__ ball, const int* __restrict__ cntv,
    const int* __restrict__ tp, const int* __restrict__ cb,
    const int* __restrict__ listall, const float* __restrict__ wlall,
    ushort* __restrict__ hout, float* __restrict__ out) {
    const int tile = blockIdx.x;
    if (tile >= tp[NE]) return;
    int e = 0;
    while (tile >= tp[e + 1]) e++;          // uniform scalar search, <=7 iters
    const int cnt = cntv[e];
    const int r0 = (tile - tp[e]) * 128;
    const int cbase = cb[e];
    const int n0 = blockIdx.y * 128;
    const int kb = IS_G1 ? 0 : blockIdx.z * (HH / SPLITK);
    const int Kd = IS_G1 ? DD : HH;         // A/B row stride (k extent)
    const int* list = listall + e * NTOK;
    const ushort* BT = Ball + (size_t)e * HH * DD;
    const float* bias = ball + e * (IS_G1 ? HH : DD);

    __shared__ __align__(16) ushort As[128 * 32];
    __shared__ __align__(16) ushort Bs[128 * 32];

    const int tid = threadIdx.x;
    const int lane = tid & 63, wv = tid >> 6;
    const int wr = (wv >> 1) * 64, wc = (wv & 1) * 64;

    // staging: lane covers row wv*16 + lane/4 (+64 on second load), 16 B at k=(lane&3)*8
    const int srow = wv * 16 + (lane >> 2);
    const int skq = (lane & 3) * 8;

    const ushort *aptr0, *aptr1;
    {
        int s0 = r0 + srow;       if (s0 >= cnt) s0 = cnt - 1;
        int s1 = r0 + 64 + srow;  if (s1 >= cnt) s1 = cnt - 1;
        if (IS_G1) {
            aptr0 = Abase + (size_t)list[s0] * Kd + skq;
            aptr1 = Abase + (size_t)list[s1] * Kd + skq;
        } else {
            aptr0 = Abase + (size_t)(cbase + s0) * Kd + kb + skq;
            aptr1 = Abase + (size_t)(cbase + s1) * Kd + kb + skq;
        }
    }
    const ushort* bptr0 = BT + (size_t)(n0 + srow) * Kd + kb + skq;
    const ushort* bptr1 = BT + (size_t)(n0 + 64 + srow) * Kd + kb + skq;

    // wave-uniform LDS bases (lane l lands at base + l*16 B = row wv*16+l/4, quarter l&3)
    ushort* As0 = As + (size_t)(wv * 16) * 32;
    ushort* As1 = As + (size_t)(64 + wv * 16) * 32;
    ushort* Bs0 = Bs + (size_t)(wv * 16) * 32;
    ushort* Bs1 = Bs + (size_t)(64 + wv * 16) * 32;

    f32x4 acc[4][4] = {};
    const int fr = lane & 15, g = lane >> 4;

    const int KT = (IS_G1 ? DD : HH / SPLITK) / 32;
    for (int kt = 0; kt < KT; kt++) {
        const int ke = kt * 32;
        gl_lds16(aptr0 + ke, As0);
        gl_lds16(aptr1 + ke, As1);
        gl_lds16(bptr0 + ke, Bs0);
        gl_lds16(bptr1 + ke, Bs1);
        __syncthreads();
        s16x8 a[4], b[4];
#pragma unroll
        for (int m = 0; m < 4; m++) a[m] = *(const s16x8*)(As + (wr + m * 16 + fr) * 32 + g * 8);
#pragma unroll
        for (int n = 0; n < 4; n++) b[n] = *(const s16x8*)(Bs + (wc + n * 16 + fr) * 32 + g * 8);
#pragma unroll
        for (int m = 0; m < 4; m++)
#pragma unroll
            for (int n = 0; n < 4; n++)
                acc[m][n] = __builtin_amdgcn_mfma_f32_16x16x32_bf16(a[m], b[n], acc[m][n], 0, 0, 0);
        __syncthreads();
    }

    // ---- epilogue ----
    if (IS_G1) {
#pragma unroll
        for (int m = 0; m < 4; m++) {
            const int rb = wr + m * 16 + (g << 2);
#pragma unroll
            for (int n = 0; n < 4; n++) {
                const int col = n0 + wc + n * 16 + fr;
                const float bv = bias[col];
#pragma unroll
                for (int r = 0; r < 4; r++) {
                    const int slot = r0 + rb + r;
                    if (slot < cnt) {
                        float v = acc[m][n][r] + bv;
                        v = v > 0.f ? v : 0.f;
                        hout[(size_t)(cbase + slot) * HH + col] = f2bf(v);
                    }
                }
            }
        }
    } else {
        const bool kz0 = (blockIdx.z == 0);
#pragma unroll
        for (int m = 0; m < 4; m++) {
            const int rb = r0 + wr + m * 16 + (g << 2);
#pragma unroll
            for (int r = 0; r < 4; r++) {
                const int slot = rb + r;
                if (slot < cnt) {
                    const int tok = list[slot];
                    const float wgt = wlall[e * NTOK + slot];
#pragma unroll
                    for (int n = 0; n < 4; n++) {
                        const int col = n0 + wc + n * 16 + fr;
                        const float bv = kz0 ? bias[col] : 0.f;
                        atomicAdd(out + (size_t)tok * DD + col,
                                  wgt * (acc[m][n][r] + bv));
                    }
                }
            }
        }
    }
}

extern "C" void kernel_launch(void* const* d_in, const int* in_sizes, int n_in,
                              void* d_out, int out_size, void* d_ws, size_t ws_size,
                              hipStream_t stream) {
    const float* x  = (const float*)d_in[0];
    const float* Wg = (const float*)d_in[1];
    const float* bg = (const float*)d_in[2];
    const float* W1 = (const float*)d_in[3];
    const float* b1 = (const float*)d_in[4];
    const float* W2 = (const float*)d_in[5];
    const float* b2 = (const float*)d_in[6];
    float* out = (float*)d_out;

    char* w = (char*)d_ws;
    int* cnt = (int*)w;                      // 8 ints
    int* tp  = (int*)(w + 64);               // 9 ints
    int* cb  = (int*)(w + 128);              // 9 ints
    size_t off = 256;
    int* list = (int*)(w + off);    off += (size_t)NE * NTOK * 4;   // 256 KB
    float* wl = (float*)(w + off);  off += (size_t)NE * NTOK * 4;   // 256 KB
    int2* topi = (int2*)(w + off);  off += (size_t)NTOK * 8;
    float2* topw = (float2*)(w + off); off += (size_t)NTOK * 8;
    off = (off + 255) & ~(size_t)255;
    ushort* W1T = (ushort*)(w + off); off += (size_t)NE * HH * DD * 2;   // 64 MB
    ushort* W2T = (ushort*)(w + off); off += (size_t)NE * HH * DD * 2;   // 64 MB
    ushort* xbf = (ushort*)(w + off); off += (size_t)NTOK * DD * 2;      // 16 MB
    ushort* hbuf = (ushort*)(w + off); off += (size_t)NTOK * 2 * HH * 2; // 128 MB

    if (ws_size < off) {  // ws too small: deterministic zero output as a signal
        hipMemsetAsync(d_out, 0, (size_t)NTOK * DD * 4, stream);
        return;
    }

    hipMemsetAsync(out, 0, (size_t)NTOK * DD * 4, stream);
    cvt_x<<<NTOK * DD / 8 / 256, 256, 0, stream>>>(x, xbf);
    gate_compute<<<NTOK / 4, 256, 0, stream>>>(x, Wg, bg, topi, topw);
    build_lists<<<NE, 256, 0, stream>>>(topi, topw, cnt, list, wl);
    tile_prefix<<<1, 64, 0, stream>>>(cnt, tp, cb);

    // W1 [e][D][H] -> W1T [e][H][D];  W2 [e][H][D] -> W2T [e][D][H]
    transpose_cvt<<<dim3(HH / 32, DD / 32, NE), dim3(32, 8), 0, stream>>>(W1, W1T, DD, HH);
    transpose_cvt<<<dim3(DD / 32, HH / 32, NE), dim3(32, 8), 0, stream>>>(W2, W2T, HH, DD);

    moe_gemm<1><<<dim3(MAXT, HH / 128), 256, 0, stream>>>(
        xbf, W1T, b1, cnt, tp, cb, list, wl, hbuf, nullptr);
    moe_gemm<0><<<dim3(MAXT, DD / 128, SPLITK), 256, 0, stream>>>(
        hbuf, W2T, b2, cnt, tp, cb, list, wl, nullptr, out);
}